// Round 3
// baseline (888.899 us; speedup 1.0000x reference)
//
#include <hip/hip_runtime.h>

// ============================================================================
// WeightPopupLayer (fp32 I/O): out = x @ (W * topk_mask(|scores|, 50%))^T + b
// Selection: exact 4-pass radix select + stable tie ranking.
// GEMM: 256^2 tile, BK=64, 8 waves (2Mx4N), dbuf LDS + XOR swizzle (0 bank
// conflicts, verified R2). R3: pipelined quadrant reads (reads for Q_{i+1}
// issued during Q_i's MFMA), 3 barriers/K-tile (was 7), counted vmcnt(8).
// Barrier legality: stage B(t+2) after all waves consumed b0,b1 (P1-end bar);
// stage A(t+2) after all waves consumed a0,a1 (P2-end bar); tile-boundary
// vmcnt(8)+bar makes tile t+1 resident before its pre-reads.
// ============================================================================

#define NTOT   16777216u    // 4096*4096
#define JDROP  8388608u     // int((1-K)*n), K=0.5
#define MDIM   8192
#define NDIM   4096
#define KDIM   4096

typedef __bf16 v8bf __attribute__((ext_vector_type(8)));
typedef float  v4f  __attribute__((ext_vector_type(4)));

__device__ __forceinline__ unsigned short f2bf(float f){
  unsigned u = __float_as_uint(f);
  u += 0x7fffu + ((u >> 16) & 1u);   // RNE
  return (unsigned short)(u >> 16);
}

// ---------------------------------------------------------------------------
// 4-pass radix select over u = bits(|s|) & 0x7FFFFFFF (monotonic in value).
// ---------------------------------------------------------------------------
__global__ void zero_hist(unsigned* hist){ hist[threadIdx.x] = 0u; }

__global__ __launch_bounds__(256) void hist_pass(const float* __restrict__ scores,
                                                 unsigned* __restrict__ hist,
                                                 const unsigned* __restrict__ state,
                                                 int p){
  // per-thread privatized byte counters pc[digit*256 + tid]; max 64/thread.
  __shared__ __align__(16) unsigned char pc[256*256];   // 64 KB
  int tid = threadIdx.x;
  unsigned* pz = (unsigned*)pc;
  #pragma unroll
  for (int k=0;k<64;++k) pz[tid + k*256] = 0u;
  __syncthreads();
  unsigned prefix = (p>0) ? state[0] : 0u;
  const float4* s4 = (const float4*)(scores + (size_t)blockIdx.x * 16384);
  for (int it=0; it<16; ++it){
    float4 v = s4[(size_t)it*256 + tid];
    #pragma unroll
    for (int e=0;e<4;++e){
      float f = (e==0)?v.x:(e==1)?v.y:(e==2)?v.z:v.w;
      unsigned u = __float_as_uint(f) & 0x7fffffffu;
      unsigned d, ok;
      if      (p==0){ d = u>>23;         ok = 1u; }
      else if (p==1){ d = (u>>15)&0xffu; ok = ((u>>23)==prefix); }
      else if (p==2){ d = (u>>7) &0xffu; ok = ((u>>15)==prefix); }
      else          { d = u & 0x7fu;     ok = ((u>>7) ==prefix); }
      if (ok) pc[d*256 + tid]++;
    }
  }
  __syncthreads();
  unsigned b = (unsigned)tid;          // bin b: sum 256 byte-columns
  const unsigned* row = (const unsigned*)(pc + b*256);
  unsigned s = 0;
  for (int kk=0;kk<64;++kk){
    int k = (kk + tid) & 63;           // stagger LDS banks
    unsigned w = row[k];
    s += (w & 0xffu) + ((w>>8)&0xffu) + ((w>>16)&0xffu) + (w>>24);
  }
  if (s) atomicAdd(&hist[b], s);
}

__global__ void select_pass(unsigned* hist, unsigned* state, int p){
  int lane = threadIdx.x;              // 64 threads = 1 wave
  unsigned c[4];
  #pragma unroll
  for (int k=0;k<4;++k){ c[k] = hist[lane*4+k]; hist[lane*4+k] = 0u; }
  unsigned s = c[0]+c[1]+c[2]+c[3];
  unsigned inc = s;
  #pragma unroll
  for (int d=1; d<64; d<<=1){
    unsigned t = (unsigned)__shfl_up((int)inc, d, 64);
    if (lane >= d) inc += t;
  }
  unsigned excl = inc - s;
  unsigned target = (p==0) ? JDROP : state[1];
  unsigned oldpre = (p==0) ? 0u    : state[0];
  if (target >= excl && target < excl + s){   // unique crossing lane
    unsigned cum = excl, digit = 0, below = 0;
    #pragma unroll
    for (int k=0;k<4;++k){
      if (target < cum + c[k]){ digit = (unsigned)lane*4u + (unsigned)k; below = cum; break; }
      cum += c[k];
    }
    state[0] = (oldpre << ((p==3)?7:8)) | digit;
    state[1] = target - below;
  }
}

// ---------------------------------------------------------------------------
// Stable tie ranking: per-4096-chunk tie counts -> scan -> flat-order rank.
// ---------------------------------------------------------------------------
__global__ __launch_bounds__(256) void tie_count(const float* __restrict__ scores,
                                                 const unsigned* __restrict__ state,
                                                 unsigned* __restrict__ tieCnt){
  unsigned T = state[0];
  int tid = threadIdx.x;
  const float4* s4 = (const float4*)(scores + (size_t)blockIdx.x * 4096);
  unsigned cnt = 0;
  for (int it=0; it<4; ++it){
    float4 v = s4[it*256 + tid];
    #pragma unroll
    for (int e=0;e<4;++e){
      float f = (e==0)?v.x:(e==1)?v.y:(e==2)?v.z:v.w;
      unsigned u = __float_as_uint(f) & 0x7fffffffu;
      cnt += (u == T) ? 1u : 0u;
    }
  }
  __shared__ unsigned r[256];
  r[tid] = cnt; __syncthreads();
  for (int s=128; s>0; s>>=1){ if (tid < s) r[tid] += r[tid+s]; __syncthreads(); }
  if (tid==0) tieCnt[blockIdx.x] = r[0];
}

__global__ __launch_bounds__(1024) void tie_scan(const unsigned* tieCnt, unsigned* tieBase){
  int tid = threadIdx.x;               // 1024 threads, 4 chunks each
  unsigned v[4], pre[4], s = 0;
  #pragma unroll
  for (int k=0;k<4;++k){ v[k] = tieCnt[tid*4+k]; pre[k] = s; s += v[k]; }
  __shared__ unsigned sc[1024];
  sc[tid] = s; __syncthreads();
  for (int d=1; d<1024; d<<=1){
    unsigned t = (tid >= d) ? sc[tid-d] : 0u;
    __syncthreads();
    sc[tid] += t;
    __syncthreads();
  }
  unsigned excl = sc[tid] - s;
  #pragma unroll
  for (int k=0;k<4;++k) tieBase[tid*4+k] = excl + pre[k];
}

// Wave-autonomous: 1 wave = 1 W-row (4096 elems), float4 loads, no barriers.
// Flat-order tie rank: lane l, slot s covers flat index 4l+s within the iter.
__global__ __launch_bounds__(256) void build_pruned(const float* __restrict__ scores,
                                                    const float* __restrict__ w,
                                                    const unsigned* __restrict__ state,
                                                    const unsigned* __restrict__ tieBase,
                                                    unsigned short* __restrict__ wpr){
  const int row  = blockIdx.x*4 + (threadIdx.x >> 6);   // 0..4095
  const int lane = threadIdx.x & 63;
  const unsigned T = state[0], D = state[1];
  unsigned runBase = tieBase[row];
  const float4* s4 = (const float4*)(scores + (size_t)row*4096);
  const float4* w4 = (const float4*)(w      + (size_t)row*4096);
  ushort4*      o4 = (ushort4*)(wpr + (size_t)row*4096);
  const unsigned long long below = (lane==0)?0ull:((~0ull) >> (64-lane));
  for (int it=0; it<16; ++it){
    float4 sv = s4[it*64 + lane];
    float4 wv = w4[it*64 + lane];
    unsigned u0 = __float_as_uint(sv.x) & 0x7fffffffu;
    unsigned u1 = __float_as_uint(sv.y) & 0x7fffffffu;
    unsigned u2 = __float_as_uint(sv.z) & 0x7fffffffu;
    unsigned u3 = __float_as_uint(sv.w) & 0x7fffffffu;
    bool t0=(u0==T), t1=(u1==T), t2=(u2==T), t3=(u3==T);
    unsigned long long b0=__ballot(t0), b1=__ballot(t1), b2=__ballot(t2), b3=__ballot(t3);
    unsigned lanesBelow = (unsigned)(__popcll(b0&below)+__popcll(b1&below)
                                   + __popcll(b2&below)+__popcll(b3&below));
    unsigned base = runBase + lanesBelow;
    unsigned r0 = base;
    unsigned r1 = base + (t0?1u:0u);
    unsigned r2 = r1   + (t1?1u:0u);
    unsigned r3 = r2   + (t2?1u:0u);
    bool k0 = (u0>T) || (t0 && r0>=D);
    bool k1 = (u1>T) || (t1 && r1>=D);
    bool k2 = (u2>T) || (t2 && r2>=D);
    bool k3 = (u3>T) || (t3 && r3>=D);
    ushort4 o;
    o.x = k0 ? f2bf(wv.x) : (unsigned short)0;
    o.y = k1 ? f2bf(wv.y) : (unsigned short)0;
    o.z = k2 ? f2bf(wv.z) : (unsigned short)0;
    o.w = k3 ? f2bf(wv.w) : (unsigned short)0;
    o4[it*64 + lane] = o;
    runBase += (unsigned)(__popcll(b0)+__popcll(b1)+__popcll(b2)+__popcll(b3));
  }
}

// ---------------------------------------------------------------------------
// x fp32 -> bf16
// ---------------------------------------------------------------------------
__global__ __launch_bounds__(256) void convert_x(const float4* __restrict__ x,
                                                 ushort4* __restrict__ xb){
  size_t i = (size_t)blockIdx.x * 256 + threadIdx.x;   // one float4 each
  float4 v = x[i];
  ushort4 o; o.x=f2bf(v.x); o.y=f2bf(v.y); o.z=f2bf(v.z); o.w=f2bf(v.w);
  xb[i] = o;
}

// ---------------------------------------------------------------------------
// GEMM
// ---------------------------------------------------------------------------
__device__ __forceinline__ void gload_lds16b(const void* g, void* l){
  __builtin_amdgcn_global_load_lds(
      (__attribute__((address_space(1))) void*)g,
      (__attribute__((address_space(3))) void*)l, 16, 0, 0);
}

// stage one matrix's 256x64 K-tile (4 x 16B loads / thread), linear LDS dest,
// inverse-swizzled global source (both-sides rule, verified 0 conflicts R2)
__device__ __forceinline__ void stage_mat(const unsigned short* __restrict__ G, int rowBase,
                                          unsigned short (* __restrict__ S)[64],
                                          int kt, int wid, int lane){
  #pragma unroll
  for (int hj=0; hj<4; ++hj){
    const int rg0 = (hj>>1)*128 + (wid*2 + (hj&1))*8;      // wave-uniform row base
    const int rg  = rg0 + (lane>>3);                       // this lane's row
    const int c16 = (lane&7) ^ (rg & 7);                   // inverse-swizzled src col
    gload_lds16b(G + (size_t)(rowBase + rg)*KDIM + kt*64 + c16*8, &S[rg0][0]);
  }
}

__device__ __forceinline__ v8bf ldsfrag(const unsigned short (* __restrict__ S)[64],
                                        int row, int kc){
  return *(const v8bf*)&S[row][(kc ^ (row & 7))*8];
}

#define BAR()   { __builtin_amdgcn_s_barrier(); asm volatile("" ::: "memory"); }

// one K-tile: quadrant-pipelined reads, 3 barriers, counted vmcnt.
__device__ __forceinline__ void ktile(const unsigned short* __restrict__ A,
                                      const unsigned short* __restrict__ B,
                                      unsigned short (* __restrict__ Asq)[64],
                                      unsigned short (* __restrict__ Bsq)[64],
                                      unsigned short (* __restrict__ AsqN)[64],
                                      unsigned short (* __restrict__ BsqN)[64],
                                      int Mb, int Nb, int t,
                                      int wr, int wc, int wid, int lane,
                                      v4f acc[8][4], v8bf a0[4][2], v8bf b0[2][2]){
  const int r16 = lane & 15, kg = lane >> 4;
  const bool pf = (t + 2 < KDIM/64);
  const bool nx = (t + 1 < KDIM/64);

  // ---- P0: issue b1 reads; Q0 = a0 x b0 -> acc[0..3][0..1]
  v8bf b1[2][2];
  #pragma unroll
  for (int n=0;n<2;++n)
    #pragma unroll
    for (int ks=0;ks<2;++ks)
      b1[n][ks] = ldsfrag(Bsq, wc*64 + (2+n)*16 + r16, ks*4 + kg);
  __builtin_amdgcn_s_setprio(1);
  #pragma unroll
  for (int i=0;i<4;++i)
    #pragma unroll
    for (int n=0;n<2;++n)
      #pragma unroll
      for (int ks=0;ks<2;++ks)
        acc[i][n] = __builtin_amdgcn_mfma_f32_16x16x32_bf16(a0[i][ks], b0[n][ks], acc[i][n], 0,0,0);
  __builtin_amdgcn_s_setprio(0);

  // ---- P1: issue a1 reads; Q1 = a0 x b1 -> acc[0..3][2..3]
  v8bf a1[4][2];
  #pragma unroll
  for (int i=0;i<4;++i)
    #pragma unroll
    for (int ks=0;ks<2;++ks)
      a1[i][ks] = ldsfrag(Asq, wr*128 + 64 + i*16 + r16, ks*4 + kg);
  __builtin_amdgcn_s_setprio(1);
  #pragma unroll
  for (int i=0;i<4;++i)
    #pragma unroll
    for (int n=0;n<2;++n)
      #pragma unroll
      for (int ks=0;ks<2;++ks)
        acc[i][2+n] = __builtin_amdgcn_mfma_f32_16x16x32_bf16(a0[i][ks], b1[n][ks], acc[i][2+n], 0,0,0);
  __builtin_amdgcn_s_setprio(0);
  BAR();   // all waves consumed b0,b1 (Q0/Q1 waited them) -> stage B legal

  // ---- P2: stage B(t+2); Q2 = a1 x b0 -> acc[4..7][0..1]
  if (pf) stage_mat(B, Nb, Bsq, t+2, wid, lane);
  __builtin_amdgcn_s_setprio(1);
  #pragma unroll
  for (int i=0;i<4;++i)
    #pragma unroll
    for (int n=0;n<2;++n)
      #pragma unroll
      for (int ks=0;ks<2;++ks)
        acc[4+i][n] = __builtin_amdgcn_mfma_f32_16x16x32_bf16(a1[i][ks], b0[n][ks], acc[4+i][n], 0,0,0);
  __builtin_amdgcn_s_setprio(0);
  BAR();   // all waves consumed a0,a1 -> stage A legal

  // ---- P3: stage A(t+2); Q3 = a1 x b1 -> acc[4..7][2..3]; drain t+1
  if (pf) stage_mat(A, Mb, Asq, t+2, wid, lane);
  __builtin_amdgcn_s_setprio(1);
  #pragma unroll
  for (int i=0;i<4;++i)
    #pragma unroll
    for (int n=0;n<2;++n)
      #pragma unroll
      for (int ks=0;ks<2;++ks)
        acc[4+i][2+n] = __builtin_amdgcn_mfma_f32_16x16x32_bf16(a1[i][ks], b1[n][ks], acc[4+i][2+n], 0,0,0);
  __builtin_amdgcn_s_setprio(0);
  if (pf) { asm volatile("s_waitcnt vmcnt(8)" ::: "memory"); }
  else    { asm volatile("s_waitcnt vmcnt(0)" ::: "memory"); }
  BAR();   // tile t+1 fully resident for every wave past this point

  // ---- pre-read next tile's a0,b0 (overlaps next P0's b1-issue + Q0 wait)
  if (nx){
    #pragma unroll
    for (int i=0;i<4;++i)
      #pragma unroll
      for (int ks=0;ks<2;++ks)
        a0[i][ks] = ldsfrag(AsqN, wr*128 + i*16 + r16, ks*4 + kg);
    #pragma unroll
    for (int n=0;n<2;++n)
      #pragma unroll
      for (int ks=0;ks<2;++ks)
        b0[n][ks] = ldsfrag(BsqN, wc*64 + n*16 + r16, ks*4 + kg);
  }
}

__global__ __launch_bounds__(512, 2) void gemm256(const unsigned short* __restrict__ A, // xb bf16 [M,K]
                                                  const unsigned short* __restrict__ B, // wpr bf16 [N,K]
                                                  const float* __restrict__ bias,
                                                  float* __restrict__ out){
  __shared__ __align__(16) unsigned short As[2][256][64];  // 64 KB
  __shared__ __align__(16) unsigned short Bs[2][256][64];  // 64 KB

  // T1: XCD-aware swizzle. 512 wgs, 8 XCDs, 64 contiguous per XCD.
  const int bid = blockIdx.x;
  const int swz = (bid & 7) * 64 + (bid >> 3);
  const int Mb  = (swz >> 4) * 256;    // 32 M-tiles
  const int Nb  = (swz & 15) * 256;    // 16 N-tiles

  const int tid  = threadIdx.x;
  const int lane = tid & 63;
  const int wid  = tid >> 6;           // 0..7
  const int wr   = wid >> 2;           // 0..1 (M)
  const int wc   = wid & 3;            // 0..3 (N)
  const int r16  = lane & 15, kg = lane >> 4;

  v4f acc[8][4];
  #pragma unroll
  for (int i=0;i<8;++i)
    #pragma unroll
    for (int n=0;n<4;++n) acc[i][n] = (v4f){0.f,0.f,0.f,0.f};

  // prologue: stage tiles 0 and 1 (16 loads), land tile 0, keep tile 1 in flight
  stage_mat(A, Mb, As[0], 0, wid, lane);
  stage_mat(B, Nb, Bs[0], 0, wid, lane);
  stage_mat(A, Mb, As[1], 1, wid, lane);
  stage_mat(B, Nb, Bs[1], 1, wid, lane);
  asm volatile("s_waitcnt vmcnt(8)" ::: "memory");
  BAR();

  // pre-read tile 0's a0,b0
  v8bf a0[4][2], b0[2][2];
  #pragma unroll
  for (int i=0;i<4;++i)
    #pragma unroll
    for (int ks=0;ks<2;++ks)
      a0[i][ks] = ldsfrag(As[0], wr*128 + i*16 + r16, ks*4 + kg);
  #pragma unroll
  for (int n=0;n<2;++n)
    #pragma unroll
    for (int ks=0;ks<2;++ks)
      b0[n][ks] = ldsfrag(Bs[0], wc*64 + n*16 + r16, ks*4 + kg);

  #pragma unroll 1
  for (int t = 0; t < KDIM/64; t += 2){
    ktile(A, B, As[0], Bs[0], As[1], Bs[1], Mb, Nb, t,   wr, wc, wid, lane, acc, a0, b0);
    ktile(A, B, As[1], Bs[1], As[0], Bs[0], Mb, Nb, t+1, wr, wc, wid, lane, acc, a0, b0);
  }

  // epilogue: C/D layout col(n) = lane&15, row(m) = (lane>>4)*4 + r
  #pragma unroll
  for (int mt=0; mt<8; ++mt){
    const int gm0 = Mb + wr*128 + mt*16 + (lane >> 4)*4;
    #pragma unroll
    for (int nt=0; nt<4; ++nt){
      const int gn = Nb + wc*64 + nt*16 + (lane & 15);
      const float bv = bias[gn];
      v4f a = acc[mt][nt];
      #pragma unroll
      for (int r=0; r<4; ++r)
        out[(size_t)(gm0 + r)*NDIM + gn] = a[r] + bv;
    }
  }
}

// ---------------------------------------------------------------------------
extern "C" void kernel_launch(void* const* d_in, const int* in_sizes, int n_in,
                              void* d_out, int out_size, void* d_ws, size_t ws_size,
                              hipStream_t stream){
  const float* x      = (const float*)d_in[0];
  const float* w      = (const float*)d_in[1];
  const float* bias   = (const float*)d_in[2];
  const float* scores = (const float*)d_in[3];
  float* out = (float*)d_out;

  char* ws = (char*)d_ws;
  unsigned* hist    = (unsigned*)(ws);                 // 1 KB
  unsigned* state   = (unsigned*)(ws + 1024);          // {prefix/T, target/D}
  unsigned* tieCnt  = (unsigned*)(ws + 2048);          // 16 KB
  unsigned* tieBase = (unsigned*)(ws + 2048 + 16384);  // 16 KB
  unsigned short* xb  = (unsigned short*)(ws + 65536);              // 64 MB
  unsigned short* wpr = (unsigned short*)(ws + 65536 + (size_t)MDIM*KDIM*2); // 32 MB

  zero_hist<<<1, 256, 0, stream>>>(hist);
  for (int p = 0; p < 4; ++p){
    hist_pass<<<1024, 256, 0, stream>>>(scores, hist, state, p);
    select_pass<<<1, 64, 0, stream>>>(hist, state, p);
  }
  tie_count<<<4096, 256, 0, stream>>>(scores, state, tieCnt);
  tie_scan<<<1, 1024, 0, stream>>>(tieCnt, tieBase);
  build_pruned<<<1024, 256, 0, stream>>>(scores, w, state, tieBase, wpr);
  convert_x<<<MDIM*KDIM/4/256, 256, 0, stream>>>((const float4*)x, (ushort4*)xb);

  gemm256<<<dim3(512), 512, 0, stream>>>(xb, wpr, bias, out);
}

// Round 4
// 735.879 us; speedup vs baseline: 1.2079x; 1.2079x over previous
//
#include <hip/hip_runtime.h>

// ============================================================================
// WeightPopupLayer (fp32 I/O): out = x @ (W * topk_mask(|scores|, 50%))^T + b
// Selection: exact radix select, 3 data passes: 8-bit (u>>23), 8-bit
// ((u>>15)&0xFF), then merged 15-bit (u&0x7FFF) via 32768-bin u32 LDS hist.
// Stable tie ranking unchanged. build_pruned: wave-autonomous (verified R3).
// GEMM: exact R2 schedule (verified 277us, 0 bank conflicts): 256^2 tile,
// BK=64, 8 waves (2Mx4N), dbuf LDS + XOR swizzle, 4-phase barriers,
// counted vmcnt(8), setprio around MFMA. (R3's cross-call fragment arrays
// caused scratch spills -> reverted.)
// ============================================================================

#define NTOT   16777216u    // 4096*4096
#define JDROP  8388608u     // int((1-K)*n), K=0.5
#define MDIM   8192
#define NDIM   4096
#define KDIM   4096

typedef __bf16 v8bf __attribute__((ext_vector_type(8)));
typedef float  v4f  __attribute__((ext_vector_type(4)));

__device__ __forceinline__ unsigned short f2bf(float f){
  unsigned u = __float_as_uint(f);
  u += 0x7fffu + ((u >> 16) & 1u);   // RNE
  return (unsigned short)(u >> 16);
}

// ---------------------------------------------------------------------------
// Radix select over u = bits(|s|) & 0x7FFFFFFF (monotonic in value).
// ---------------------------------------------------------------------------
__global__ void zero_hist(unsigned* hist, unsigned* h15g){
  // 128 blocks x 256 thr: zero h15g (32768 u32); block 0 also zeroes hist.
  h15g[blockIdx.x*256 + threadIdx.x] = 0u;
  if (blockIdx.x==0) hist[threadIdx.x] = 0u;
}

__global__ __launch_bounds__(256) void hist_pass(const float* __restrict__ scores,
                                                 unsigned* __restrict__ hist,
                                                 const unsigned* __restrict__ state,
                                                 int p){
  // per-thread privatized byte counters pc[digit*256 + tid]; max 64/thread.
  __shared__ __align__(16) unsigned char pc[256*256];   // 64 KB
  int tid = threadIdx.x;
  unsigned* pz = (unsigned*)pc;
  #pragma unroll
  for (int k=0;k<64;++k) pz[tid + k*256] = 0u;
  __syncthreads();
  unsigned prefix = (p>0) ? state[0] : 0u;
  const float4* s4 = (const float4*)(scores + (size_t)blockIdx.x * 16384);
  for (int it=0; it<16; ++it){
    float4 v = s4[(size_t)it*256 + tid];
    #pragma unroll
    for (int e=0;e<4;++e){
      float f = (e==0)?v.x:(e==1)?v.y:(e==2)?v.z:v.w;
      unsigned u = __float_as_uint(f) & 0x7fffffffu;
      unsigned d, ok;
      if (p==0){ d = u>>23;         ok = 1u; }
      else     { d = (u>>15)&0xffu; ok = ((u>>23)==prefix); }
      if (ok) pc[d*256 + tid]++;
    }
  }
  __syncthreads();
  unsigned b = (unsigned)tid;          // bin b: sum 256 byte-columns
  const unsigned* row = (const unsigned*)(pc + b*256);
  unsigned s = 0;
  for (int kk=0;kk<64;++kk){
    int k = (kk + tid) & 63;           // stagger LDS banks
    unsigned w = row[k];
    s += (w & 0xffu) + ((w>>8)&0xffu) + ((w>>16)&0xffu) + (w>>24);
  }
  if (s) atomicAdd(&hist[b], s);
}

__global__ void select_pass(unsigned* hist, unsigned* state, int p){
  int lane = threadIdx.x;              // 64 threads = 1 wave
  unsigned c[4];
  #pragma unroll
  for (int k=0;k<4;++k){ c[k] = hist[lane*4+k]; hist[lane*4+k] = 0u; }
  unsigned s = c[0]+c[1]+c[2]+c[3];
  unsigned inc = s;
  #pragma unroll
  for (int d=1; d<64; d<<=1){
    unsigned t = (unsigned)__shfl_up((int)inc, d, 64);
    if (lane >= d) inc += t;
  }
  unsigned excl = inc - s;
  unsigned target = (p==0) ? JDROP : state[1];
  unsigned oldpre = (p==0) ? 0u    : state[0];
  if (target >= excl && target < excl + s){   // unique crossing lane
    unsigned cum = excl, digit = 0, below = 0;
    #pragma unroll
    for (int k=0;k<4;++k){
      if (target < cum + c[k]){ digit = (unsigned)lane*4u + (unsigned)k; below = cum; break; }
      cum += c[k];
    }
    state[0] = (oldpre << 8) | digit;
    state[1] = target - below;
  }
}

// Merged low-15-bit pass: 32768-bin u32 LDS hist of u&0x7FFF restricted to
// (u>>15)==prefix16. Restricted set is ~1.2M elems -> LDS atomics uncontended.
__global__ __launch_bounds__(256) void hist15_pass(const float* __restrict__ scores,
                                                   const unsigned* __restrict__ state,
                                                   unsigned* __restrict__ h15g){
  __shared__ unsigned h[32768];        // 128 KB
  int tid = threadIdx.x;
  #pragma unroll
  for (int k=0;k<128;++k) h[tid + k*256] = 0u;
  __syncthreads();
  const unsigned pre16 = state[0];
  const float4* s4 = (const float4*)(scores + (size_t)blockIdx.x * 16384);
  for (int it=0; it<16; ++it){
    float4 v = s4[(size_t)it*256 + tid];
    #pragma unroll
    for (int e=0;e<4;++e){
      float f = (e==0)?v.x:(e==1)?v.y:(e==2)?v.z:v.w;
      unsigned u = __float_as_uint(f) & 0x7fffffffu;
      if ((u>>15) == pre16) atomicAdd(&h[u & 0x7fffu], 1u);
    }
  }
  __syncthreads();
  #pragma unroll
  for (int k=0;k<128;++k){
    unsigned v = h[tid + k*256];
    if (v) atomicAdd(&h15g[tid + k*256], v);
  }
}

__global__ void select15(const unsigned* __restrict__ h15g, unsigned* state){
  int lane = threadIdx.x;              // 64 threads = 1 wave; 512 bins/lane
  unsigned s = 0;
  for (int k=0;k<512;++k) s += h15g[lane*512 + k];
  unsigned inc = s;
  #pragma unroll
  for (int d=1; d<64; d<<=1){
    unsigned t = (unsigned)__shfl_up((int)inc, d, 64);
    if (lane >= d) inc += t;
  }
  unsigned excl = inc - s;
  unsigned target = state[1];
  if (target >= excl && target < excl + s){   // unique crossing lane
    unsigned cum = excl, digit = 0, below = 0;
    for (int k=0;k<512;++k){
      unsigned c = h15g[lane*512 + k];
      if (target < cum + c){ digit = (unsigned)(lane*512 + k); below = cum; break; }
      cum += c;
    }
    state[0] = (state[0] << 15) | digit;   // full 31-bit threshold T
    state[1] = target - below;             // D ties to drop
  }
}

// ---------------------------------------------------------------------------
// Stable tie ranking: per-4096-chunk tie counts -> scan -> flat-order rank.
// ---------------------------------------------------------------------------
__global__ __launch_bounds__(256) void tie_count(const float* __restrict__ scores,
                                                 const unsigned* __restrict__ state,
                                                 unsigned* __restrict__ tieCnt){
  unsigned T = state[0];
  int tid = threadIdx.x;
  const float4* s4 = (const float4*)(scores + (size_t)blockIdx.x * 4096);
  unsigned cnt = 0;
  for (int it=0; it<4; ++it){
    float4 v = s4[it*256 + tid];
    #pragma unroll
    for (int e=0;e<4;++e){
      float f = (e==0)?v.x:(e==1)?v.y:(e==2)?v.z:v.w;
      unsigned u = __float_as_uint(f) & 0x7fffffffu;
      cnt += (u == T) ? 1u : 0u;
    }
  }
  __shared__ unsigned r[256];
  r[tid] = cnt; __syncthreads();
  for (int s=128; s>0; s>>=1){ if (tid < s) r[tid] += r[tid+s]; __syncthreads(); }
  if (tid==0) tieCnt[blockIdx.x] = r[0];
}

__global__ __launch_bounds__(1024) void tie_scan(const unsigned* tieCnt, unsigned* tieBase){
  int tid = threadIdx.x;               // 1024 threads, 4 chunks each
  unsigned v[4], pre[4], s = 0;
  #pragma unroll
  for (int k=0;k<4;++k){ v[k] = tieCnt[tid*4+k]; pre[k] = s; s += v[k]; }
  __shared__ unsigned sc[1024];
  sc[tid] = s; __syncthreads();
  for (int d=1; d<1024; d<<=1){
    unsigned t = (tid >= d) ? sc[tid-d] : 0u;
    __syncthreads();
    sc[tid] += t;
    __syncthreads();
  }
  unsigned excl = sc[tid] - s;
  #pragma unroll
  for (int k=0;k<4;++k) tieBase[tid*4+k] = excl + pre[k];
}

// Wave-autonomous: 1 wave = 1 W-row (4096 elems), float4 loads, no barriers.
__global__ __launch_bounds__(256) void build_pruned(const float* __restrict__ scores,
                                                    const float* __restrict__ w,
                                                    const unsigned* __restrict__ state,
                                                    const unsigned* __restrict__ tieBase,
                                                    unsigned short* __restrict__ wpr){
  const int row  = blockIdx.x*4 + (threadIdx.x >> 6);   // 0..4095
  const int lane = threadIdx.x & 63;
  const unsigned T = state[0], D = state[1];
  unsigned runBase = tieBase[row];
  const float4* s4 = (const float4*)(scores + (size_t)row*4096);
  const float4* w4 = (const float4*)(w      + (size_t)row*4096);
  ushort4*      o4 = (ushort4*)(wpr + (size_t)row*4096);
  const unsigned long long below = (lane==0)?0ull:((~0ull) >> (64-lane));
  for (int it=0; it<16; ++it){
    float4 sv = s4[it*64 + lane];
    float4 wv = w4[it*64 + lane];
    unsigned u0 = __float_as_uint(sv.x) & 0x7fffffffu;
    unsigned u1 = __float_as_uint(sv.y) & 0x7fffffffu;
    unsigned u2 = __float_as_uint(sv.z) & 0x7fffffffu;
    unsigned u3 = __float_as_uint(sv.w) & 0x7fffffffu;
    bool t0=(u0==T), t1=(u1==T), t2=(u2==T), t3=(u3==T);
    unsigned long long b0=__ballot(t0), b1=__ballot(t1), b2=__ballot(t2), b3=__ballot(t3);
    unsigned lanesBelow = (unsigned)(__popcll(b0&below)+__popcll(b1&below)
                                   + __popcll(b2&below)+__popcll(b3&below));
    unsigned base = runBase + lanesBelow;
    unsigned r0 = base;
    unsigned r1 = base + (t0?1u:0u);
    unsigned r2 = r1   + (t1?1u:0u);
    unsigned r3 = r2   + (t2?1u:0u);
    bool k0 = (u0>T) || (t0 && r0>=D);
    bool k1 = (u1>T) || (t1 && r1>=D);
    bool k2 = (u2>T) || (t2 && r2>=D);
    bool k3 = (u3>T) || (t3 && r3>=D);
    ushort4 o;
    o.x = k0 ? f2bf(wv.x) : (unsigned short)0;
    o.y = k1 ? f2bf(wv.y) : (unsigned short)0;
    o.z = k2 ? f2bf(wv.z) : (unsigned short)0;
    o.w = k3 ? f2bf(wv.w) : (unsigned short)0;
    o4[it*64 + lane] = o;
    runBase += (unsigned)(__popcll(b0)+__popcll(b1)+__popcll(b2)+__popcll(b3));
  }
}

// ---------------------------------------------------------------------------
// x fp32 -> bf16
// ---------------------------------------------------------------------------
__global__ __launch_bounds__(256) void convert_x(const float4* __restrict__ x,
                                                 ushort4* __restrict__ xb){
  size_t i = (size_t)blockIdx.x * 256 + threadIdx.x;   // one float4 each
  float4 v = x[i];
  ushort4 o; o.x=f2bf(v.x); o.y=f2bf(v.y); o.z=f2bf(v.z); o.w=f2bf(v.w);
  xb[i] = o;
}

// ---------------------------------------------------------------------------
// GEMM (exact R2 schedule, verified 277us / 0 bank conflicts)
// ---------------------------------------------------------------------------
__device__ __forceinline__ void gload_lds16b(const void* g, void* l){
  __builtin_amdgcn_global_load_lds(
      (__attribute__((address_space(1))) void*)g,
      (__attribute__((address_space(3))) void*)l, 16, 0, 0);
}

__device__ __forceinline__ void stage_mat(const unsigned short* __restrict__ G, int rowBase,
                                          unsigned short (* __restrict__ S)[64],
                                          int kt, int wid, int lane){
  #pragma unroll
  for (int hj=0; hj<4; ++hj){
    const int rg0 = (hj>>1)*128 + (wid*2 + (hj&1))*8;      // wave-uniform row base
    const int rg  = rg0 + (lane>>3);                       // this lane's row
    const int c16 = (lane&7) ^ (rg & 7);                   // inverse-swizzled src col
    gload_lds16b(G + (size_t)(rowBase + rg)*KDIM + kt*64 + c16*8, &S[rg0][0]);
  }
}

__device__ __forceinline__ v8bf ldsfrag(const unsigned short (* __restrict__ S)[64],
                                        int row, int kc){
  return *(const v8bf*)&S[row][(kc ^ (row & 7))*8];
}

#define BAR()   { __builtin_amdgcn_s_barrier(); asm volatile("" ::: "memory"); }
#define LGKM0() asm volatile("s_waitcnt lgkmcnt(0)" ::: "memory")

__device__ __forceinline__ void ktile(const unsigned short* __restrict__ A,
                                      const unsigned short* __restrict__ B,
                                      unsigned short (* __restrict__ Asq)[64],
                                      unsigned short (* __restrict__ Bsq)[64],
                                      int Mb, int Nb, int t,
                                      int wr, int wc, int wid, int lane,
                                      v4f acc[8][4]){
  const int r16 = lane & 15, kg = lane >> 4;
  const bool pf = (t + 2 < KDIM/64);

  // ---- P0: A m0-3 + B n0-1 reads; Q0 = acc[0..3][0..1]
  v8bf a0[4][2], b0[2][2];
  #pragma unroll
  for (int i=0;i<4;++i)
    #pragma unroll
    for (int ks=0;ks<2;++ks)
      a0[i][ks] = ldsfrag(Asq, wr*128 + i*16 + r16, ks*4 + kg);
  #pragma unroll
  for (int n=0;n<2;++n)
    #pragma unroll
    for (int ks=0;ks<2;++ks)
      b0[n][ks] = ldsfrag(Bsq, wc*64 + n*16 + r16, ks*4 + kg);
  BAR(); LGKM0();
  __builtin_amdgcn_s_setprio(1);
  #pragma unroll
  for (int i=0;i<4;++i)
    #pragma unroll
    for (int n=0;n<2;++n)
      #pragma unroll
      for (int ks=0;ks<2;++ks)
        acc[i][n] = __builtin_amdgcn_mfma_f32_16x16x32_bf16(a0[i][ks], b0[n][ks], acc[i][n], 0,0,0);
  __builtin_amdgcn_s_setprio(0);
  BAR();

  // ---- P1: B n2-3 reads; Q1 = acc[0..3][2..3] (a0 x b1)
  v8bf b1[2][2];
  #pragma unroll
  for (int n=0;n<2;++n)
    #pragma unroll
    for (int ks=0;ks<2;++ks)
      b1[n][ks] = ldsfrag(Bsq, wc*64 + (2+n)*16 + r16, ks*4 + kg);
  BAR(); LGKM0();
  __builtin_amdgcn_s_setprio(1);
  #pragma unroll
  for (int i=0;i<4;++i)
    #pragma unroll
    for (int n=0;n<2;++n)
      #pragma unroll
      for (int ks=0;ks<2;++ks)
        acc[i][2+n] = __builtin_amdgcn_mfma_f32_16x16x32_bf16(a0[i][ks], b1[n][ks], acc[i][2+n], 0,0,0);
  __builtin_amdgcn_s_setprio(0);
  BAR();   // all waves' B reads of tile t complete past this point

  // ---- P2: A m4-7 reads; issue stage B(t+2); Q2 = acc[4..7][0..1] (a1 x b0)
  v8bf a1[4][2];
  #pragma unroll
  for (int i=0;i<4;++i)
    #pragma unroll
    for (int ks=0;ks<2;++ks)
      a1[i][ks] = ldsfrag(Asq, wr*128 + 64 + i*16 + r16, ks*4 + kg);
  if (pf) stage_mat(B, Nb, Bsq, t+2, wid, lane);
  BAR(); LGKM0();
  __builtin_amdgcn_s_setprio(1);
  #pragma unroll
  for (int i=0;i<4;++i)
    #pragma unroll
    for (int n=0;n<2;++n)
      #pragma unroll
      for (int ks=0;ks<2;++ks)
        acc[4+i][n] = __builtin_amdgcn_mfma_f32_16x16x32_bf16(a1[i][ks], b0[n][ks], acc[4+i][n], 0,0,0);
  __builtin_amdgcn_s_setprio(0);
  BAR();   // all waves' A reads of tile t complete past this point

  // ---- P3: issue stage A(t+2); Q3 = acc[4..7][2..3] (a1 x b1); drain t+1
  if (pf) stage_mat(A, Mb, Asq, t+2, wid, lane);
  __builtin_amdgcn_s_setprio(1);
  #pragma unroll
  for (int i=0;i<4;++i)
    #pragma unroll
    for (int n=0;n<2;++n)
      #pragma unroll
      for (int ks=0;ks<2;++ks)
        acc[4+i][2+n] = __builtin_amdgcn_mfma_f32_16x16x32_bf16(a1[i][ks], b1[n][ks], acc[4+i][2+n], 0,0,0);
  __builtin_amdgcn_s_setprio(0);
  if (pf) { asm volatile("s_waitcnt vmcnt(8)" ::: "memory"); }
  else    { asm volatile("s_waitcnt vmcnt(0)" ::: "memory"); }
  BAR();   // tile t+1 fully resident for every wave past this point
}

__global__ __launch_bounds__(512, 2) void gemm256(const unsigned short* __restrict__ A, // xb bf16 [M,K]
                                                  const unsigned short* __restrict__ B, // wpr bf16 [N,K]
                                                  const float* __restrict__ bias,
                                                  float* __restrict__ out){
  __shared__ __align__(16) unsigned short As[2][256][64];  // 64 KB
  __shared__ __align__(16) unsigned short Bs[2][256][64];  // 64 KB

  // T1: XCD-aware swizzle. 512 wgs, 8 XCDs, 64 contiguous per XCD.
  const int bid = blockIdx.x;
  const int swz = (bid & 7) * 64 + (bid >> 3);
  const int Mb  = (swz >> 4) * 256;    // 32 M-tiles
  const int Nb  = (swz & 15) * 256;    // 16 N-tiles

  const int tid  = threadIdx.x;
  const int lane = tid & 63;
  const int wid  = tid >> 6;           // 0..7
  const int wr   = wid >> 2;           // 0..1 (M)
  const int wc   = wid & 3;            // 0..3 (N)

  v4f acc[8][4];
  #pragma unroll
  for (int i=0;i<8;++i)
    #pragma unroll
    for (int n=0;n<4;++n) acc[i][n] = (v4f){0.f,0.f,0.f,0.f};

  // prologue: stage tiles 0 and 1 (16 loads), land tile 0, keep tile 1 in flight
  stage_mat(A, Mb, As[0], 0, wid, lane);
  stage_mat(B, Nb, Bs[0], 0, wid, lane);
  stage_mat(A, Mb, As[1], 1, wid, lane);
  stage_mat(B, Nb, Bs[1], 1, wid, lane);
  asm volatile("s_waitcnt vmcnt(8)" ::: "memory");
  BAR();

  #pragma unroll 1
  for (int t = 0; t < KDIM/64; t += 2){
    ktile(A, B, As[0], Bs[0], Mb, Nb, t,   wr, wc, wid, lane, acc);
    ktile(A, B, As[1], Bs[1], Mb, Nb, t+1, wr, wc, wid, lane, acc);
  }

  // epilogue: C/D layout col(n) = lane&15, row(m) = (lane>>4)*4 + r
  #pragma unroll
  for (int mt=0; mt<8; ++mt){
    const int gm0 = Mb + wr*128 + mt*16 + (lane >> 4)*4;
    #pragma unroll
    for (int nt=0; nt<4; ++nt){
      const int gn = Nb + wc*64 + nt*16 + (lane & 15);
      const float bv = bias[gn];
      v4f a = acc[mt][nt];
      #pragma unroll
      for (int r=0; r<4; ++r)
        out[(size_t)(gm0 + r)*NDIM + gn] = a[r] + bv;
    }
  }
}

// ---------------------------------------------------------------------------
extern "C" void kernel_launch(void* const* d_in, const int* in_sizes, int n_in,
                              void* d_out, int out_size, void* d_ws, size_t ws_size,
                              hipStream_t stream){
  const float* x      = (const float*)d_in[0];
  const float* w      = (const float*)d_in[1];
  const float* bias   = (const float*)d_in[2];
  const float* scores = (const float*)d_in[3];
  float* out = (float*)d_out;

  char* ws = (char*)d_ws;
  unsigned* hist    = (unsigned*)(ws);                 // 1 KB
  unsigned* state   = (unsigned*)(ws + 1024);          // {prefix/T, target/D}
  unsigned* tieCnt  = (unsigned*)(ws + 2048);          // 16 KB
  unsigned* tieBase = (unsigned*)(ws + 2048 + 16384);  // 16 KB
  unsigned short* xb  = (unsigned short*)(ws + 65536);              // 64 MB
  unsigned short* wpr = (unsigned short*)(ws + 65536 + (size_t)MDIM*KDIM*2); // 32 MB
  // h15g (128 KB) overlays the head of xb: dead before convert_x writes xb.
  unsigned* h15g = (unsigned*)(ws + 65536);

  zero_hist<<<128, 256, 0, stream>>>(hist, h15g);
  for (int p = 0; p < 2; ++p){
    hist_pass<<<1024, 256, 0, stream>>>(scores, hist, state, p);
    select_pass<<<1, 64, 0, stream>>>(hist, state, p);
  }
  hist15_pass<<<1024, 256, 0, stream>>>(scores, state, h15g);
  select15<<<1, 64, 0, stream>>>(h15g, state);
  tie_count<<<4096, 256, 0, stream>>>(scores, state, tieCnt);
  tie_scan<<<1, 1024, 0, stream>>>(tieCnt, tieBase);
  build_pruned<<<1024, 256, 0, stream>>>(scores, w, state, tieBase, wpr);
  convert_x<<<MDIM*KDIM/4/256, 256, 0, stream>>>((const float4*)x, (ushort4*)xb);

  gemm256<<<dim3(512), 512, 0, stream>>>(xb, wpr, bias, out);
}

// Round 5
// 682.005 us; speedup vs baseline: 1.3034x; 1.0790x over previous
//
#include <hip/hip_runtime.h>

// ============================================================================
// WeightPopupLayer (fp32 I/O): out = x @ (W * topk_mask(|scores|, 50%))^T + b
// Selection: exact radix select, 3 data passes: 8-bit (u>>23), 8-bit
// ((u>>15)&0xFF) via byte-counter hist (contention-free for clustered bits),
// then merged 15-bit (u&0x7FFF) via 32768-bin u32 LDS hist at 8 waves/CU.
// Tie ranking: tie_count pass + scan fused into build_pruned (per-block
// strided prefix over tieCnt). build_pruned wave-autonomous (verified R3/R4).
// GEMM: exact R2/R4 schedule (verified 277-279us, 0 bank conflicts): 256^2
// tile, BK=64, 8 waves (2Mx4N), dbuf LDS + XOR swizzle, 4-phase barriers,
// counted vmcnt(8), setprio around MFMA.
// ============================================================================

#define NTOT   16777216u    // 4096*4096
#define JDROP  8388608u     // int((1-K)*n), K=0.5
#define MDIM   8192
#define NDIM   4096
#define KDIM   4096

typedef __bf16 v8bf __attribute__((ext_vector_type(8)));
typedef float  v4f  __attribute__((ext_vector_type(4)));

__device__ __forceinline__ unsigned short f2bf(float f){
  unsigned u = __float_as_uint(f);
  u += 0x7fffu + ((u >> 16) & 1u);   // RNE
  return (unsigned short)(u >> 16);
}

// ---------------------------------------------------------------------------
// Radix select over u = bits(|s|) & 0x7FFFFFFF (monotonic in value).
// ---------------------------------------------------------------------------
__global__ void zero_hist(unsigned* hist, unsigned* h15g){
  // 128 blocks x 256 thr: zero h15g (32768 u32); block 0 also zeroes hist.
  h15g[blockIdx.x*256 + threadIdx.x] = 0u;
  if (blockIdx.x==0) hist[threadIdx.x] = 0u;
}

__global__ __launch_bounds__(256) void hist_pass(const float* __restrict__ scores,
                                                 unsigned* __restrict__ hist,
                                                 const unsigned* __restrict__ state,
                                                 int p){
  // per-thread privatized byte counters pc[digit*256 + tid]; max 64/thread.
  __shared__ __align__(16) unsigned char pc[256*256];   // 64 KB
  int tid = threadIdx.x;
  unsigned* pz = (unsigned*)pc;
  #pragma unroll
  for (int k=0;k<64;++k) pz[tid + k*256] = 0u;
  __syncthreads();
  unsigned prefix = (p>0) ? state[0] : 0u;
  const float4* s4 = (const float4*)(scores + (size_t)blockIdx.x * 16384);
  for (int it=0; it<16; ++it){
    float4 v = s4[(size_t)it*256 + tid];
    #pragma unroll
    for (int e=0;e<4;++e){
      float f = (e==0)?v.x:(e==1)?v.y:(e==2)?v.z:v.w;
      unsigned u = __float_as_uint(f) & 0x7fffffffu;
      unsigned d, ok;
      if (p==0){ d = u>>23;         ok = 1u; }
      else     { d = (u>>15)&0xffu; ok = ((u>>23)==prefix); }
      if (ok) pc[d*256 + tid]++;
    }
  }
  __syncthreads();
  unsigned b = (unsigned)tid;          // bin b: sum 256 byte-columns
  const unsigned* row = (const unsigned*)(pc + b*256);
  unsigned s = 0;
  for (int kk=0;kk<64;++kk){
    int k = (kk + tid) & 63;           // stagger LDS banks
    unsigned w = row[k];
    s += (w & 0xffu) + ((w>>8)&0xffu) + ((w>>16)&0xffu) + (w>>24);
  }
  if (s) atomicAdd(&hist[b], s);
}

__global__ void select_pass(unsigned* hist, unsigned* state, int p){
  int lane = threadIdx.x;              // 64 threads = 1 wave
  unsigned c[4];
  #pragma unroll
  for (int k=0;k<4;++k){ c[k] = hist[lane*4+k]; hist[lane*4+k] = 0u; }
  unsigned s = c[0]+c[1]+c[2]+c[3];
  unsigned inc = s;
  #pragma unroll
  for (int d=1; d<64; d<<=1){
    unsigned t = (unsigned)__shfl_up((int)inc, d, 64);
    if (lane >= d) inc += t;
  }
  unsigned excl = inc - s;
  unsigned target = (p==0) ? JDROP : state[1];
  unsigned oldpre = (p==0) ? 0u    : state[0];
  if (target >= excl && target < excl + s){   // unique crossing lane
    unsigned cum = excl, digit = 0, below = 0;
    #pragma unroll
    for (int k=0;k<4;++k){
      if (target < cum + c[k]){ digit = (unsigned)lane*4u + (unsigned)k; below = cum; break; }
      cum += c[k];
    }
    state[0] = (oldpre << 8) | digit;
    state[1] = target - below;
  }
}

// Merged low-15-bit pass: 32768-bin u32 LDS hist of u&0x7FFF restricted to
// (u>>15)==prefix16. 256 blocks x 512 thr (8 waves/CU), 128 elems/thread.
// Low bits of the restricted set are ~uniform -> LDS atomics uncontended.
__global__ __launch_bounds__(512) void hist15_pass(const float* __restrict__ scores,
                                                   const unsigned* __restrict__ state,
                                                   unsigned* __restrict__ h15g){
  __shared__ unsigned h[32768];        // 128 KB
  int tid = threadIdx.x;
  #pragma unroll
  for (int k=0;k<64;++k) h[tid + k*512] = 0u;
  __syncthreads();
  const unsigned pre16 = state[0];
  const float4* s4 = (const float4*)scores;
  const size_t base = (size_t)blockIdx.x * 16384;   // float4 units
  for (int it=0; it<32; ++it){
    float4 v = s4[base + (size_t)it*512 + tid];
    #pragma unroll
    for (int e=0;e<4;++e){
      float f = (e==0)?v.x:(e==1)?v.y:(e==2)?v.z:v.w;
      unsigned u = __float_as_uint(f) & 0x7fffffffu;
      if ((u>>15) == pre16) atomicAdd(&h[u & 0x7fffu], 1u);
    }
  }
  __syncthreads();
  #pragma unroll
  for (int k=0;k<64;++k){
    unsigned v = h[tid + k*512];
    if (v) atomicAdd(&h15g[tid + k*512], v);
  }
}

__global__ __launch_bounds__(256) void select15(const unsigned* __restrict__ h15g,
                                                unsigned* state){
  int tid = threadIdx.x;               // 256 threads; 128 bins/thread
  unsigned s = 0;
  for (int k=0;k<128;++k) s += h15g[tid*128 + k];
  __shared__ unsigned sc[256];
  sc[tid] = s; __syncthreads();
  for (int d=1; d<256; d<<=1){         // Hillis-Steele inclusive scan
    unsigned t = (tid >= d) ? sc[tid-d] : 0u;
    __syncthreads();
    sc[tid] += t;
    __syncthreads();
  }
  unsigned excl = sc[tid] - s;
  unsigned target = state[1];
  if (target >= excl && target < excl + s){   // unique crossing thread
    unsigned cum = excl, digit = 0, below = 0;
    for (int k=0;k<128;++k){
      unsigned c = h15g[tid*128 + k];
      if (target < cum + c){ digit = (unsigned)(tid*128 + k); below = cum; break; }
      cum += c;
    }
    state[0] = (state[0] << 15) | digit;   // full 31-bit threshold T
    state[1] = target - below;             // D ties to drop
  }
}

// ---------------------------------------------------------------------------
// Stable tie ranking: per-row (4096-elem) tie counts; scan fused into build.
// ---------------------------------------------------------------------------
__global__ __launch_bounds__(256) void tie_count(const float* __restrict__ scores,
                                                 const unsigned* __restrict__ state,
                                                 unsigned* __restrict__ tieCnt){
  unsigned T = state[0];
  int tid = threadIdx.x;
  const float4* s4 = (const float4*)(scores + (size_t)blockIdx.x * 4096);
  unsigned cnt = 0;
  for (int it=0; it<4; ++it){
    float4 v = s4[it*256 + tid];
    #pragma unroll
    for (int e=0;e<4;++e){
      float f = (e==0)?v.x:(e==1)?v.y:(e==2)?v.z:v.w;
      unsigned u = __float_as_uint(f) & 0x7fffffffu;
      cnt += (u == T) ? 1u : 0u;
    }
  }
  __shared__ unsigned r[256];
  r[tid] = cnt; __syncthreads();
  for (int s=128; s>0; s>>=1){ if (tid < s) r[tid] += r[tid+s]; __syncthreads(); }
  if (tid==0) tieCnt[blockIdx.x] = r[0];
}

// Wave-autonomous: 1 wave = 1 W-row (4096 elems), float4 loads.
// Prologue computes this block's tie-rank base from tieCnt directly
// (strided sum + LDS tree reduce) -- replaces the tie_scan kernel.
__global__ __launch_bounds__(256) void build_pruned(const float* __restrict__ scores,
                                                    const float* __restrict__ w,
                                                    const unsigned* __restrict__ state,
                                                    const unsigned* __restrict__ tieCnt,
                                                    unsigned short* __restrict__ wpr){
  const int tid  = threadIdx.x;
  const int lane = tid & 63;
  const int wv   = tid >> 6;                            // 0..3
  const int rowFirst = blockIdx.x*4;
  const int row  = rowFirst + wv;                       // 0..4095

  // base = sum of tieCnt[0..rowFirst)
  unsigned part = 0;
  for (int j = tid; j < rowFirst; j += 256) part += tieCnt[j];
  __shared__ unsigned red[256];
  red[tid] = part; __syncthreads();
  for (int s=128; s>0; s>>=1){ if (tid < s) red[tid] += red[tid+s]; __syncthreads(); }
  unsigned runBase = red[0];
  #pragma unroll
  for (int i=0;i<3;++i) if (i < wv) runBase += tieCnt[rowFirst + i];

  const unsigned T = state[0], D = state[1];
  const float4* s4 = (const float4*)(scores + (size_t)row*4096);
  const float4* w4 = (const float4*)(w      + (size_t)row*4096);
  ushort4*      o4 = (ushort4*)(wpr + (size_t)row*4096);
  const unsigned long long below = (lane==0)?0ull:((~0ull) >> (64-lane));
  for (int it=0; it<16; ++it){
    float4 sv = s4[it*64 + lane];
    float4 wvv = w4[it*64 + lane];
    unsigned u0 = __float_as_uint(sv.x) & 0x7fffffffu;
    unsigned u1 = __float_as_uint(sv.y) & 0x7fffffffu;
    unsigned u2 = __float_as_uint(sv.z) & 0x7fffffffu;
    unsigned u3 = __float_as_uint(sv.w) & 0x7fffffffu;
    bool t0=(u0==T), t1=(u1==T), t2=(u2==T), t3=(u3==T);
    unsigned long long b0=__ballot(t0), b1=__ballot(t1), b2=__ballot(t2), b3=__ballot(t3);
    unsigned lanesBelow = (unsigned)(__popcll(b0&below)+__popcll(b1&below)
                                   + __popcll(b2&below)+__popcll(b3&below));
    unsigned base = runBase + lanesBelow;
    unsigned r0 = base;
    unsigned r1 = base + (t0?1u:0u);
    unsigned r2 = r1   + (t1?1u:0u);
    unsigned r3 = r2   + (t2?1u:0u);
    bool k0 = (u0>T) || (t0 && r0>=D);
    bool k1 = (u1>T) || (t1 && r1>=D);
    bool k2 = (u2>T) || (t2 && r2>=D);
    bool k3 = (u3>T) || (t3 && r3>=D);
    ushort4 o;
    o.x = k0 ? f2bf(wvv.x) : (unsigned short)0;
    o.y = k1 ? f2bf(wvv.y) : (unsigned short)0;
    o.z = k2 ? f2bf(wvv.z) : (unsigned short)0;
    o.w = k3 ? f2bf(wvv.w) : (unsigned short)0;
    o4[it*64 + lane] = o;
    runBase += (unsigned)(__popcll(b0)+__popcll(b1)+__popcll(b2)+__popcll(b3));
  }
}

// ---------------------------------------------------------------------------
// x fp32 -> bf16
// ---------------------------------------------------------------------------
__global__ __launch_bounds__(256) void convert_x(const float4* __restrict__ x,
                                                 ushort4* __restrict__ xb){
  size_t i = (size_t)blockIdx.x * 256 + threadIdx.x;   // one float4 each
  float4 v = x[i];
  ushort4 o; o.x=f2bf(v.x); o.y=f2bf(v.y); o.z=f2bf(v.z); o.w=f2bf(v.w);
  xb[i] = o;
}

// ---------------------------------------------------------------------------
// GEMM (exact R2/R4 schedule, verified 277-279us / 0 bank conflicts)
// ---------------------------------------------------------------------------
__device__ __forceinline__ void gload_lds16b(const void* g, void* l){
  __builtin_amdgcn_global_load_lds(
      (__attribute__((address_space(1))) void*)g,
      (__attribute__((address_space(3))) void*)l, 16, 0, 0);
}

__device__ __forceinline__ void stage_mat(const unsigned short* __restrict__ G, int rowBase,
                                          unsigned short (* __restrict__ S)[64],
                                          int kt, int wid, int lane){
  #pragma unroll
  for (int hj=0; hj<4; ++hj){
    const int rg0 = (hj>>1)*128 + (wid*2 + (hj&1))*8;      // wave-uniform row base
    const int rg  = rg0 + (lane>>3);                       // this lane's row
    const int c16 = (lane&7) ^ (rg & 7);                   // inverse-swizzled src col
    gload_lds16b(G + (size_t)(rowBase + rg)*KDIM + kt*64 + c16*8, &S[rg0][0]);
  }
}

__device__ __forceinline__ v8bf ldsfrag(const unsigned short (* __restrict__ S)[64],
                                        int row, int kc){
  return *(const v8bf*)&S[row][(kc ^ (row & 7))*8];
}

#define BAR()   { __builtin_amdgcn_s_barrier(); asm volatile("" ::: "memory"); }
#define LGKM0() asm volatile("s_waitcnt lgkmcnt(0)" ::: "memory")

__device__ __forceinline__ void ktile(const unsigned short* __restrict__ A,
                                      const unsigned short* __restrict__ B,
                                      unsigned short (* __restrict__ Asq)[64],
                                      unsigned short (* __restrict__ Bsq)[64],
                                      int Mb, int Nb, int t,
                                      int wr, int wc, int wid, int lane,
                                      v4f acc[8][4]){
  const int r16 = lane & 15, kg = lane >> 4;
  const bool pf = (t + 2 < KDIM/64);

  // ---- P0: A m0-3 + B n0-1 reads; Q0 = acc[0..3][0..1]
  v8bf a0[4][2], b0[2][2];
  #pragma unroll
  for (int i=0;i<4;++i)
    #pragma unroll
    for (int ks=0;ks<2;++ks)
      a0[i][ks] = ldsfrag(Asq, wr*128 + i*16 + r16, ks*4 + kg);
  #pragma unroll
  for (int n=0;n<2;++n)
    #pragma unroll
    for (int ks=0;ks<2;++ks)
      b0[n][ks] = ldsfrag(Bsq, wc*64 + n*16 + r16, ks*4 + kg);
  BAR(); LGKM0();
  __builtin_amdgcn_s_setprio(1);
  #pragma unroll
  for (int i=0;i<4;++i)
    #pragma unroll
    for (int n=0;n<2;++n)
      #pragma unroll
      for (int ks=0;ks<2;++ks)
        acc[i][n] = __builtin_amdgcn_mfma_f32_16x16x32_bf16(a0[i][ks], b0[n][ks], acc[i][n], 0,0,0);
  __builtin_amdgcn_s_setprio(0);
  BAR();

  // ---- P1: B n2-3 reads; Q1 = acc[0..3][2..3] (a0 x b1)
  v8bf b1[2][2];
  #pragma unroll
  for (int n=0;n<2;++n)
    #pragma unroll
    for (int ks=0;ks<2;++ks)
      b1[n][ks] = ldsfrag(Bsq, wc*64 + (2+n)*16 + r16, ks*4 + kg);
  BAR(); LGKM0();
  __builtin_amdgcn_s_setprio(1);
  #pragma unroll
  for (int i=0;i<4;++i)
    #pragma unroll
    for (int n=0;n<2;++n)
      #pragma unroll
      for (int ks=0;ks<2;++ks)
        acc[i][2+n] = __builtin_amdgcn_mfma_f32_16x16x32_bf16(a0[i][ks], b1[n][ks], acc[i][2+n], 0,0,0);
  __builtin_amdgcn_s_setprio(0);
  BAR();   // all waves' B reads of tile t complete past this point

  // ---- P2: A m4-7 reads; issue stage B(t+2); Q2 = acc[4..7][0..1] (a1 x b0)
  v8bf a1[4][2];
  #pragma unroll
  for (int i=0;i<4;++i)
    #pragma unroll
    for (int ks=0;ks<2;++ks)
      a1[i][ks] = ldsfrag(Asq, wr*128 + 64 + i*16 + r16, ks*4 + kg);
  if (pf) stage_mat(B, Nb, Bsq, t+2, wid, lane);
  BAR(); LGKM0();
  __builtin_amdgcn_s_setprio(1);
  #pragma unroll
  for (int i=0;i<4;++i)
    #pragma unroll
    for (int n=0;n<2;++n)
      #pragma unroll
      for (int ks=0;ks<2;++ks)
        acc[4+i][n] = __builtin_amdgcn_mfma_f32_16x16x32_bf16(a1[i][ks], b0[n][ks], acc[4+i][n], 0,0,0);
  __builtin_amdgcn_s_setprio(0);
  BAR();   // all waves' A reads of tile t complete past this point

  // ---- P3: issue stage A(t+2); Q3 = acc[4..7][2..3] (a1 x b1); drain t+1
  if (pf) stage_mat(A, Mb, Asq, t+2, wid, lane);
  __builtin_amdgcn_s_setprio(1);
  #pragma unroll
  for (int i=0;i<4;++i)
    #pragma unroll
    for (int n=0;n<2;++n)
      #pragma unroll
      for (int ks=0;ks<2;++ks)
        acc[4+i][2+n] = __builtin_amdgcn_mfma_f32_16x16x32_bf16(a1[i][ks], b1[n][ks], acc[4+i][2+n], 0,0,0);
  __builtin_amdgcn_s_setprio(0);
  if (pf) { asm volatile("s_waitcnt vmcnt(8)" ::: "memory"); }
  else    { asm volatile("s_waitcnt vmcnt(0)" ::: "memory"); }
  BAR();   // tile t+1 fully resident for every wave past this point
}

__global__ __launch_bounds__(512, 2) void gemm256(const unsigned short* __restrict__ A, // xb bf16 [M,K]
                                                  const unsigned short* __restrict__ B, // wpr bf16 [N,K]
                                                  const float* __restrict__ bias,
                                                  float* __restrict__ out){
  __shared__ __align__(16) unsigned short As[2][256][64];  // 64 KB
  __shared__ __align__(16) unsigned short Bs[2][256][64];  // 64 KB

  // T1: XCD-aware swizzle. 512 wgs, 8 XCDs, 64 contiguous per XCD.
  const int bid = blockIdx.x;
  const int swz = (bid & 7) * 64 + (bid >> 3);
  const int Mb  = (swz >> 4) * 256;    // 32 M-tiles
  const int Nb  = (swz & 15) * 256;    // 16 N-tiles

  const int tid  = threadIdx.x;
  const int lane = tid & 63;
  const int wid  = tid >> 6;           // 0..7
  const int wr   = wid >> 2;           // 0..1 (M)
  const int wc   = wid & 3;            // 0..3 (N)

  v4f acc[8][4];
  #pragma unroll
  for (int i=0;i<8;++i)
    #pragma unroll
    for (int n=0;n<4;++n) acc[i][n] = (v4f){0.f,0.f,0.f,0.f};

  // prologue: stage tiles 0 and 1 (16 loads), land tile 0, keep tile 1 in flight
  stage_mat(A, Mb, As[0], 0, wid, lane);
  stage_mat(B, Nb, Bs[0], 0, wid, lane);
  stage_mat(A, Mb, As[1], 1, wid, lane);
  stage_mat(B, Nb, Bs[1], 1, wid, lane);
  asm volatile("s_waitcnt vmcnt(8)" ::: "memory");
  BAR();

  #pragma unroll 1
  for (int t = 0; t < KDIM/64; t += 2){
    ktile(A, B, As[0], Bs[0], Mb, Nb, t,   wr, wc, wid, lane, acc);
    ktile(A, B, As[1], Bs[1], Mb, Nb, t+1, wr, wc, wid, lane, acc);
  }

  // epilogue: C/D layout col(n) = lane&15, row(m) = (lane>>4)*4 + r
  #pragma unroll
  for (int mt=0; mt<8; ++mt){
    const int gm0 = Mb + wr*128 + mt*16 + (lane >> 4)*4;
    #pragma unroll
    for (int nt=0; nt<4; ++nt){
      const int gn = Nb + wc*64 + nt*16 + (lane & 15);
      const float bv = bias[gn];
      v4f a = acc[mt][nt];
      #pragma unroll
      for (int r=0; r<4; ++r)
        out[(size_t)(gm0 + r)*NDIM + gn] = a[r] + bv;
    }
  }
}

// ---------------------------------------------------------------------------
extern "C" void kernel_launch(void* const* d_in, const int* in_sizes, int n_in,
                              void* d_out, int out_size, void* d_ws, size_t ws_size,
                              hipStream_t stream){
  const float* x      = (const float*)d_in[0];
  const float* w      = (const float*)d_in[1];
  const float* bias   = (const float*)d_in[2];
  const float* scores = (const float*)d_in[3];
  float* out = (float*)d_out;

  char* ws = (char*)d_ws;
  unsigned* hist    = (unsigned*)(ws);                 // 1 KB
  unsigned* state   = (unsigned*)(ws + 1024);          // {prefix/T, target/D}
  unsigned* tieCnt  = (unsigned*)(ws + 2048);          // 16 KB
  unsigned short* xb  = (unsigned short*)(ws + 65536);              // 64 MB
  unsigned short* wpr = (unsigned short*)(ws + 65536 + (size_t)MDIM*KDIM*2); // 32 MB
  // h15g (128 KB) overlays the head of xb: dead before convert_x writes xb.
  unsigned* h15g = (unsigned*)(ws + 65536);

  zero_hist<<<128, 256, 0, stream>>>(hist, h15g);
  for (int p = 0; p < 2; ++p){
    hist_pass<<<1024, 256, 0, stream>>>(scores, hist, state, p);
    select_pass<<<1, 64, 0, stream>>>(hist, state, p);
  }
  hist15_pass<<<256, 512, 0, stream>>>(scores, state, h15g);
  select15<<<1, 256, 0, stream>>>(h15g, state);
  tie_count<<<4096, 256, 0, stream>>>(scores, state, tieCnt);
  build_pruned<<<1024, 256, 0, stream>>>(scores, w, state, tieCnt, wpr);
  convert_x<<<MDIM*KDIM/4/256, 256, 0, stream>>>((const float4*)x, (ushort4*)xb);

  gemm256<<<dim3(512), 512, 0, stream>>>(xb, wpr, bias, out);
}

// Round 6
// 671.465 us; speedup vs baseline: 1.3238x; 1.0157x over previous
//
#include <hip/hip_runtime.h>

// ============================================================================
// WeightPopupLayer (fp32 I/O): out = x @ (W * topk_mask(|scores|, 50%))^T + b
// Selection: exact radix select, 3 data passes: 8-bit (u>>23), 8-bit
// ((u>>15)&0xFF) via byte-counter hist, merged 15-bit (u&0x7FFF) via
// 32768-bin u32 LDS hist at 8 waves/CU.
// Tie handling (R6): build_pruned keeps all ties provisionally and appends
// their flat indices to a list (atomic); tie_fixup ranks the (few) ties by
// flat index and zeroes the first D in wpr. Replaces the 64MB tie_count pass.
// GEMM (R6): R2/R4 schedule, but WITHOUT the inline-asm lgkmcnt(0) drains --
// ds_reads are normal loads, the compiler emits precise counted lgkmcnt
// before each dependent MFMA, so first MFMAs start while tail reads land.
// Barriers / vmcnt(8) / stage-legality identical to the verified schedule.
// ============================================================================

#define NTOT   16777216u    // 4096*4096
#define JDROP  8388608u     // int((1-K)*n), K=0.5
#define MDIM   8192
#define NDIM   4096
#define KDIM   4096
#define TIECAP 1048576u     // tie-list capacity (actual expected: tens)

typedef __bf16 v8bf __attribute__((ext_vector_type(8)));
typedef float  v4f  __attribute__((ext_vector_type(4)));

__device__ __forceinline__ unsigned short f2bf(float f){
  unsigned u = __float_as_uint(f);
  u += 0x7fffu + ((u >> 16) & 1u);   // RNE
  return (unsigned short)(u >> 16);
}

// ---------------------------------------------------------------------------
// Radix select over u = bits(|s|) & 0x7FFFFFFF (monotonic in value).
// ---------------------------------------------------------------------------
__global__ void zero_hist(unsigned* hist, unsigned* h15g, unsigned* tieCnt){
  // 128 blocks x 256 thr: zero h15g (32768 u32); block 0 also zeroes hist+cnt.
  h15g[blockIdx.x*256 + threadIdx.x] = 0u;
  if (blockIdx.x==0) hist[threadIdx.x] = 0u;
  if (blockIdx.x==0 && threadIdx.x==0) *tieCnt = 0u;
}

__global__ __launch_bounds__(256) void hist_pass(const float* __restrict__ scores,
                                                 unsigned* __restrict__ hist,
                                                 const unsigned* __restrict__ state,
                                                 int p){
  // per-thread privatized byte counters pc[digit*256 + tid]; max 64/thread.
  __shared__ __align__(16) unsigned char pc[256*256];   // 64 KB
  int tid = threadIdx.x;
  unsigned* pz = (unsigned*)pc;
  #pragma unroll
  for (int k=0;k<64;++k) pz[tid + k*256] = 0u;
  __syncthreads();
  unsigned prefix = (p>0) ? state[0] : 0u;
  const float4* s4 = (const float4*)(scores + (size_t)blockIdx.x * 16384);
  for (int it=0; it<16; ++it){
    float4 v = s4[(size_t)it*256 + tid];
    #pragma unroll
    for (int e=0;e<4;++e){
      float f = (e==0)?v.x:(e==1)?v.y:(e==2)?v.z:v.w;
      unsigned u = __float_as_uint(f) & 0x7fffffffu;
      unsigned d, ok;
      if (p==0){ d = u>>23;         ok = 1u; }
      else     { d = (u>>15)&0xffu; ok = ((u>>23)==prefix); }
      if (ok) pc[d*256 + tid]++;
    }
  }
  __syncthreads();
  unsigned b = (unsigned)tid;          // bin b: sum 256 byte-columns
  const unsigned* row = (const unsigned*)(pc + b*256);
  unsigned s = 0;
  for (int kk=0;kk<64;++kk){
    int k = (kk + tid) & 63;           // stagger LDS banks
    unsigned w = row[k];
    s += (w & 0xffu) + ((w>>8)&0xffu) + ((w>>16)&0xffu) + (w>>24);
  }
  if (s) atomicAdd(&hist[b], s);
}

__global__ void select_pass(unsigned* hist, unsigned* state, int p){
  int lane = threadIdx.x;              // 64 threads = 1 wave
  unsigned c[4];
  #pragma unroll
  for (int k=0;k<4;++k){ c[k] = hist[lane*4+k]; hist[lane*4+k] = 0u; }
  unsigned s = c[0]+c[1]+c[2]+c[3];
  unsigned inc = s;
  #pragma unroll
  for (int d=1; d<64; d<<=1){
    unsigned t = (unsigned)__shfl_up((int)inc, d, 64);
    if (lane >= d) inc += t;
  }
  unsigned excl = inc - s;
  unsigned target = (p==0) ? JDROP : state[1];
  unsigned oldpre = (p==0) ? 0u    : state[0];
  if (target >= excl && target < excl + s){   // unique crossing lane
    unsigned cum = excl, digit = 0, below = 0;
    #pragma unroll
    for (int k=0;k<4;++k){
      if (target < cum + c[k]){ digit = (unsigned)lane*4u + (unsigned)k; below = cum; break; }
      cum += c[k];
    }
    state[0] = (oldpre << 8) | digit;
    state[1] = target - below;
  }
}

// Merged low-15-bit pass: 32768-bin u32 LDS hist of u&0x7FFF restricted to
// (u>>15)==prefix16. 256 blocks x 512 thr (8 waves/CU), 128 elems/thread.
__global__ __launch_bounds__(512) void hist15_pass(const float* __restrict__ scores,
                                                   const unsigned* __restrict__ state,
                                                   unsigned* __restrict__ h15g){
  __shared__ unsigned h[32768];        // 128 KB
  int tid = threadIdx.x;
  #pragma unroll
  for (int k=0;k<64;++k) h[tid + k*512] = 0u;
  __syncthreads();
  const unsigned pre16 = state[0];
  const float4* s4 = (const float4*)scores;
  const size_t base = (size_t)blockIdx.x * 16384;   // float4 units
  for (int it=0; it<32; ++it){
    float4 v = s4[base + (size_t)it*512 + tid];
    #pragma unroll
    for (int e=0;e<4;++e){
      float f = (e==0)?v.x:(e==1)?v.y:(e==2)?v.z:v.w;
      unsigned u = __float_as_uint(f) & 0x7fffffffu;
      if ((u>>15) == pre16) atomicAdd(&h[u & 0x7fffu], 1u);
    }
  }
  __syncthreads();
  #pragma unroll
  for (int k=0;k<64;++k){
    unsigned v = h[tid + k*512];
    if (v) atomicAdd(&h15g[tid + k*512], v);
  }
}

__global__ __launch_bounds__(256) void select15(const unsigned* __restrict__ h15g,
                                                unsigned* state){
  int tid = threadIdx.x;               // 256 threads; 128 bins/thread
  unsigned s = 0;
  for (int k=0;k<128;++k) s += h15g[tid*128 + k];
  __shared__ unsigned sc[256];
  sc[tid] = s; __syncthreads();
  for (int d=1; d<256; d<<=1){         // Hillis-Steele inclusive scan
    unsigned t = (tid >= d) ? sc[tid-d] : 0u;
    __syncthreads();
    sc[tid] += t;
    __syncthreads();
  }
  unsigned excl = sc[tid] - s;
  unsigned target = state[1];
  if (target >= excl && target < excl + s){   // unique crossing thread
    unsigned cum = excl, digit = 0, below = 0;
    for (int k=0;k<128;++k){
      unsigned c = h15g[tid*128 + k];
      if (target < cum + c){ digit = (unsigned)(tid*128 + k); below = cum; break; }
      cum += c;
    }
    state[0] = (state[0] << 15) | digit;   // full 31-bit threshold T
    state[1] = target - below;             // D ties to drop
  }
}

// ---------------------------------------------------------------------------
// build_pruned: wave-autonomous, 1 wave = 1 W-row. Ties (u==T) are KEPT
// provisionally and their flat indices appended to tieList; tie_fixup then
// zeroes the first D by flat order. No tie_count pass, no prefix machinery.
// ---------------------------------------------------------------------------
__global__ __launch_bounds__(256) void build_pruned(const float* __restrict__ scores,
                                                    const float* __restrict__ w,
                                                    const unsigned* __restrict__ state,
                                                    unsigned* __restrict__ tieCnt,
                                                    unsigned* __restrict__ tieList,
                                                    unsigned short* __restrict__ wpr){
  const int row  = blockIdx.x*4 + (threadIdx.x >> 6);   // 0..4095
  const int lane = threadIdx.x & 63;
  const unsigned T = state[0];
  const float4* s4 = (const float4*)(scores + (size_t)row*4096);
  const float4* w4 = (const float4*)(w      + (size_t)row*4096);
  ushort4*      o4 = (ushort4*)(wpr + (size_t)row*4096);
  const unsigned rowBase = (unsigned)row * 4096u;
  for (int it=0; it<16; ++it){
    float4 sv = s4[it*64 + lane];
    float4 wv = w4[it*64 + lane];
    unsigned u0 = __float_as_uint(sv.x) & 0x7fffffffu;
    unsigned u1 = __float_as_uint(sv.y) & 0x7fffffffu;
    unsigned u2 = __float_as_uint(sv.z) & 0x7fffffffu;
    unsigned u3 = __float_as_uint(sv.w) & 0x7fffffffu;
    ushort4 o;
    o.x = (u0 >= T) ? f2bf(wv.x) : (unsigned short)0;
    o.y = (u1 >= T) ? f2bf(wv.y) : (unsigned short)0;
    o.z = (u2 >= T) ? f2bf(wv.z) : (unsigned short)0;
    o.w = (u3 >= T) ? f2bf(wv.w) : (unsigned short)0;
    o4[it*64 + lane] = o;
    const unsigned ebase = rowBase + (unsigned)(it*64 + lane)*4u;
    if (u0 == T){ unsigned p = atomicAdd(tieCnt,1u); if (p < TIECAP) tieList[p] = ebase;    }
    if (u1 == T){ unsigned p = atomicAdd(tieCnt,1u); if (p < TIECAP) tieList[p] = ebase+1u; }
    if (u2 == T){ unsigned p = atomicAdd(tieCnt,1u); if (p < TIECAP) tieList[p] = ebase+2u; }
    if (u3 == T){ unsigned p = atomicAdd(tieCnt,1u); if (p < TIECAP) tieList[p] = ebase+3u; }
  }
}

// Rank ties by flat index; zero the first D (stable ascending-sort semantics).
__global__ __launch_bounds__(256) void tie_fixup(const unsigned* __restrict__ tieCnt,
                                                 const unsigned* __restrict__ tieList,
                                                 const unsigned* __restrict__ state,
                                                 unsigned short* __restrict__ wpr){
  unsigned n = *tieCnt; if (n > TIECAP) n = TIECAP;
  const unsigned D = state[1];
  if (D == 0) return;
  for (unsigned j = threadIdx.x; j < n; j += 256){
    unsigned idx = tieList[j];
    unsigned rank = 0;
    for (unsigned k = 0; k < n; ++k) rank += (tieList[k] < idx) ? 1u : 0u;
    if (rank < D) wpr[idx] = (unsigned short)0;
  }
}

// ---------------------------------------------------------------------------
// x fp32 -> bf16
// ---------------------------------------------------------------------------
__global__ __launch_bounds__(256) void convert_x(const float4* __restrict__ x,
                                                 ushort4* __restrict__ xb){
  size_t i = (size_t)blockIdx.x * 256 + threadIdx.x;   // one float4 each
  float4 v = x[i];
  ushort4 o; o.x=f2bf(v.x); o.y=f2bf(v.y); o.z=f2bf(v.z); o.w=f2bf(v.w);
  xb[i] = o;
}

// ---------------------------------------------------------------------------
// GEMM (R2/R4 schedule; R6: compiler-counted lgkm waits, no forced drain)
// ---------------------------------------------------------------------------
__device__ __forceinline__ void gload_lds16b(const void* g, void* l){
  __builtin_amdgcn_global_load_lds(
      (__attribute__((address_space(1))) void*)g,
      (__attribute__((address_space(3))) void*)l, 16, 0, 0);
}

__device__ __forceinline__ void stage_mat(const unsigned short* __restrict__ G, int rowBase,
                                          unsigned short (* __restrict__ S)[64],
                                          int kt, int wid, int lane){
  #pragma unroll
  for (int hj=0; hj<4; ++hj){
    const int rg0 = (hj>>1)*128 + (wid*2 + (hj&1))*8;      // wave-uniform row base
    const int rg  = rg0 + (lane>>3);                       // this lane's row
    const int c16 = (lane&7) ^ (rg & 7);                   // inverse-swizzled src col
    gload_lds16b(G + (size_t)(rowBase + rg)*KDIM + kt*64 + c16*8, &S[rg0][0]);
  }
}

__device__ __forceinline__ v8bf ldsfrag(const unsigned short (* __restrict__ S)[64],
                                        int row, int kc){
  return *(const v8bf*)&S[row][(kc ^ (row & 7))*8];
}

#define BAR()   { __builtin_amdgcn_s_barrier(); asm volatile("" ::: "memory"); }

__device__ __forceinline__ void ktile(const unsigned short* __restrict__ A,
                                      const unsigned short* __restrict__ B,
                                      unsigned short (* __restrict__ Asq)[64],
                                      unsigned short (* __restrict__ Bsq)[64],
                                      int Mb, int Nb, int t,
                                      int wr, int wc, int wid, int lane,
                                      v4f acc[8][4]){
  const int r16 = lane & 15, kg = lane >> 4;
  const bool pf = (t + 2 < KDIM/64);

  // ---- P0: A m0-3 + B n0-1 reads; Q0 = acc[0..3][0..1]
  v8bf a0[4][2], b0[2][2];
  #pragma unroll
  for (int i=0;i<4;++i)
    #pragma unroll
    for (int ks=0;ks<2;++ks)
      a0[i][ks] = ldsfrag(Asq, wr*128 + i*16 + r16, ks*4 + kg);
  #pragma unroll
  for (int n=0;n<2;++n)
    #pragma unroll
    for (int ks=0;ks<2;++ks)
      b0[n][ks] = ldsfrag(Bsq, wc*64 + n*16 + r16, ks*4 + kg);
  BAR();
  __builtin_amdgcn_s_setprio(1);
  #pragma unroll
  for (int i=0;i<4;++i)
    #pragma unroll
    for (int n=0;n<2;++n)
      #pragma unroll
      for (int ks=0;ks<2;++ks)
        acc[i][n] = __builtin_amdgcn_mfma_f32_16x16x32_bf16(a0[i][ks], b0[n][ks], acc[i][n], 0,0,0);
  __builtin_amdgcn_s_setprio(0);
  BAR();

  // ---- P1: B n2-3 reads; Q1 = acc[0..3][2..3] (a0 x b1)
  v8bf b1[2][2];
  #pragma unroll
  for (int n=0;n<2;++n)
    #pragma unroll
    for (int ks=0;ks<2;++ks)
      b1[n][ks] = ldsfrag(Bsq, wc*64 + (2+n)*16 + r16, ks*4 + kg);
  BAR();
  __builtin_amdgcn_s_setprio(1);
  #pragma unroll
  for (int i=0;i<4;++i)
    #pragma unroll
    for (int n=0;n<2;++n)
      #pragma unroll
      for (int ks=0;ks<2;++ks)
        acc[i][2+n] = __builtin_amdgcn_mfma_f32_16x16x32_bf16(a0[i][ks], b1[n][ks], acc[i][2+n], 0,0,0);
  __builtin_amdgcn_s_setprio(0);
  BAR();   // all waves' B reads of tile t complete past this point

  // ---- P2: A m4-7 reads; issue stage B(t+2); Q2 = acc[4..7][0..1] (a1 x b0)
  v8bf a1[4][2];
  #pragma unroll
  for (int i=0;i<4;++i)
    #pragma unroll
    for (int ks=0;ks<2;++ks)
      a1[i][ks] = ldsfrag(Asq, wr*128 + 64 + i*16 + r16, ks*4 + kg);
  if (pf) stage_mat(B, Nb, Bsq, t+2, wid, lane);
  BAR();
  __builtin_amdgcn_s_setprio(1);
  #pragma unroll
  for (int i=0;i<4;++i)
    #pragma unroll
    for (int n=0;n<2;++n)
      #pragma unroll
      for (int ks=0;ks<2;++ks)
        acc[4+i][n] = __builtin_amdgcn_mfma_f32_16x16x32_bf16(a1[i][ks], b0[n][ks], acc[4+i][n], 0,0,0);
  __builtin_amdgcn_s_setprio(0);
  BAR();   // all waves' A reads of tile t complete past this point

  // ---- P3: issue stage A(t+2); Q3 = acc[4..7][2..3] (a1 x b1); drain t+1
  if (pf) stage_mat(A, Mb, Asq, t+2, wid, lane);
  __builtin_amdgcn_s_setprio(1);
  #pragma unroll
  for (int i=0;i<4;++i)
    #pragma unroll
    for (int n=0;n<2;++n)
      #pragma unroll
      for (int ks=0;ks<2;++ks)
        acc[4+i][2+n] = __builtin_amdgcn_mfma_f32_16x16x32_bf16(a1[i][ks], b1[n][ks], acc[4+i][2+n], 0,0,0);
  __builtin_amdgcn_s_setprio(0);
  if (pf) { asm volatile("s_waitcnt vmcnt(8)" ::: "memory"); }
  else    { asm volatile("s_waitcnt vmcnt(0)" ::: "memory"); }
  BAR();   // tile t+1 fully resident for every wave past this point
}

__global__ __launch_bounds__(512, 2) void gemm256(const unsigned short* __restrict__ A, // xb bf16 [M,K]
                                                  const unsigned short* __restrict__ B, // wpr bf16 [N,K]
                                                  const float* __restrict__ bias,
                                                  float* __restrict__ out){
  __shared__ __align__(16) unsigned short As[2][256][64];  // 64 KB
  __shared__ __align__(16) unsigned short Bs[2][256][64];  // 64 KB

  // T1: XCD-aware swizzle. 512 wgs, 8 XCDs, 64 contiguous per XCD.
  const int bid = blockIdx.x;
  const int swz = (bid & 7) * 64 + (bid >> 3);
  const int Mb  = (swz >> 4) * 256;    // 32 M-tiles
  const int Nb  = (swz & 15) * 256;    // 16 N-tiles

  const int tid  = threadIdx.x;
  const int lane = tid & 63;
  const int wid  = tid >> 6;           // 0..7
  const int wr   = wid >> 2;           // 0..1 (M)
  const int wc   = wid & 3;            // 0..3 (N)

  v4f acc[8][4];
  #pragma unroll
  for (int i=0;i<8;++i)
    #pragma unroll
    for (int n=0;n<4;++n) acc[i][n] = (v4f){0.f,0.f,0.f,0.f};

  // prologue: stage tiles 0 and 1 (16 loads), land tile 0, keep tile 1 in flight
  stage_mat(A, Mb, As[0], 0, wid, lane);
  stage_mat(B, Nb, Bs[0], 0, wid, lane);
  stage_mat(A, Mb, As[1], 1, wid, lane);
  stage_mat(B, Nb, Bs[1], 1, wid, lane);
  asm volatile("s_waitcnt vmcnt(8)" ::: "memory");
  BAR();

  #pragma unroll 1
  for (int t = 0; t < KDIM/64; t += 2){
    ktile(A, B, As[0], Bs[0], Mb, Nb, t,   wr, wc, wid, lane, acc);
    ktile(A, B, As[1], Bs[1], Mb, Nb, t+1, wr, wc, wid, lane, acc);
  }

  // epilogue: C/D layout col(n) = lane&15, row(m) = (lane>>4)*4 + r
  #pragma unroll
  for (int mt=0; mt<8; ++mt){
    const int gm0 = Mb + wr*128 + mt*16 + (lane >> 4)*4;
    #pragma unroll
    for (int nt=0; nt<4; ++nt){
      const int gn = Nb + wc*64 + nt*16 + (lane & 15);
      const float bv = bias[gn];
      v4f a = acc[mt][nt];
      #pragma unroll
      for (int r=0; r<4; ++r)
        out[(size_t)(gm0 + r)*NDIM + gn] = a[r] + bv;
    }
  }
}

// ---------------------------------------------------------------------------
extern "C" void kernel_launch(void* const* d_in, const int* in_sizes, int n_in,
                              void* d_out, int out_size, void* d_ws, size_t ws_size,
                              hipStream_t stream){
  const float* x      = (const float*)d_in[0];
  const float* w      = (const float*)d_in[1];
  const float* bias   = (const float*)d_in[2];
  const float* scores = (const float*)d_in[3];
  float* out = (float*)d_out;

  char* ws = (char*)d_ws;
  unsigned* hist    = (unsigned*)(ws);                 // 1 KB
  unsigned* state   = (unsigned*)(ws + 1024);          // {prefix/T, target/D}
  unsigned* tieCnt  = (unsigned*)(ws + 2048);          // 4 B atomic counter
  unsigned short* xb  = (unsigned short*)(ws + 65536);              // 64 MB
  unsigned short* wpr = (unsigned short*)(ws + 65536 + (size_t)MDIM*KDIM*2); // 32 MB
  // h15g (128 KB) overlays the head of xb; tieList (4 MB) overlays xb+32MB.
  // Both are dead before convert_x writes xb (fixup runs before convert_x).
  unsigned* h15g    = (unsigned*)(ws + 65536);
  unsigned* tieList = (unsigned*)(ws + 65536 + 33554432);

  zero_hist<<<128, 256, 0, stream>>>(hist, h15g, tieCnt);
  for (int p = 0; p < 2; ++p){
    hist_pass<<<1024, 256, 0, stream>>>(scores, hist, state, p);
    select_pass<<<1, 64, 0, stream>>>(hist, state, p);
  }
  hist15_pass<<<256, 512, 0, stream>>>(scores, state, h15g);
  select15<<<1, 256, 0, stream>>>(h15g, state);
  build_pruned<<<1024, 256, 0, stream>>>(scores, w, state, tieCnt, tieList, wpr);
  tie_fixup<<<1, 256, 0, stream>>>(tieCnt, tieList, state, wpr);
  convert_x<<<MDIM*KDIM/4/256, 256, 0, stream>>>((const float4*)x, (ushort4*)xb);

  gemm256<<<dim3(512), 512, 0, stream>>>(xb, wpr, bias, out);
}